// Round 6
// baseline (275.424 us; speedup 1.0000x reference)
//
#include <hip/hip_runtime.h>
#include <stdint.h>
#include <math.h>

typedef __bf16 bf16_t;
typedef __attribute__((ext_vector_type(8))) __bf16 bf16x8;
typedef __attribute__((ext_vector_type(4))) __bf16 bf16x4;
typedef __attribute__((ext_vector_type(4))) float f32x4;

#define N_TOK 4096
#define D_MODEL 1024
#define HEADS 16
#define DH 64
// p = exp(8*dot - 8.125) = exp2(dot*C1 - C2); constant shift cancels in softmax.
#define C1 11.541560327111707f   // 8 * log2(e)
#define C2 11.721897207207671f   // 8.125 * log2(e)

// async global->LDS 16B copy (dest = wave-uniform base + lane*16)
__device__ __forceinline__ void async_copy16(const void* g, void* l) {
    __builtin_amdgcn_global_load_lds(
        (const __attribute__((address_space(1))) unsigned int*)g,
        (__attribute__((address_space(3))) unsigned int*)l, 16, 0, 0);
}

// ---------------- cast x -> bf16 ----------------
__global__ __launch_bounds__(256) void cast_x_kernel(const float* __restrict__ x,
                                                     bf16_t* __restrict__ xb) {
    int i = (blockIdx.x * 256 + threadIdx.x) * 4;
    float4 v = *(const float4*)(x + i);
    bf16x4 o;
    o[0] = (bf16_t)v.x; o[1] = (bf16_t)v.y; o[2] = (bf16_t)v.z; o[3] = (bf16_t)v.w;
    *(bf16x4*)(xb + i) = o;
}

// ------- transpose + cast W[k][n] -> Wt[n][k] bf16 (q,k,v into one 3072-row buf) ----
__global__ __launch_bounds__(256) void transpose_w_kernel(
    const float* __restrict__ W0, const float* __restrict__ W1,
    const float* __restrict__ W2, const float* __restrict__ W3,
    bf16_t* __restrict__ T0, bf16_t* __restrict__ T1,
    bf16_t* __restrict__ T2, bf16_t* __restrict__ T3) {
    __shared__ bf16_t t[64][72];
    const float* W; bf16_t* T;
    switch (blockIdx.z) {
        case 0: W = W0; T = T0; break;
        case 1: W = W1; T = T1; break;
        case 2: W = W2; T = T2; break;
        default: W = W3; T = T3; break;
    }
    int k0 = blockIdx.x * 64, n0 = blockIdx.y * 64;
    int tx = threadIdx.x & 63, ty = threadIdx.x >> 6;
#pragma unroll
    for (int i = 0; i < 16; i++) {
        int kl = ty * 16 + i;
        t[kl][tx] = (bf16_t)W[(size_t)(k0 + kl) * D_MODEL + n0 + tx];
    }
    __syncthreads();
#pragma unroll
    for (int i = 0; i < 16; i++) {
        int nl = ty * 16 + i;
        T[(size_t)(n0 + nl) * D_MODEL + k0 + tx] = t[tx][nl];
    }
}

// ------- 128x128 MFMA GEMM, swizzled global_load_lds staging, 4 waves x (64x64) -----
// C[M][ldc] tile = A[M][1024] * Bt[N][1024]^T ; optional fused L2-norm per 64-col head
template <int WRITE_F32, int NORM>
__global__ __launch_bounds__(256) void gemm_tile(const bf16_t* __restrict__ A,
                                                 const bf16_t* __restrict__ Bt,
                                                 void* __restrict__ Cout, int ldc) {
    constexpr int K = D_MODEL;
    __shared__ __align__(16) bf16_t As[128 * 32];
    __shared__ __align__(16) bf16_t Bs[128 * 32];
    const int tid = threadIdx.x;
    const int m0 = blockIdx.y * 128;
    const int n0 = blockIdx.x * 128;
    const int wave = tid >> 6;
    const int lane = tid & 63;
    const int l15 = lane & 15;
    const int quad = lane >> 4;
    const int wm = (wave >> 1) * 64;
    const int wn = (wave & 1) * 64;
    const int fsw = quad ^ ((l15 >> 1) & 3);      // read-side swizzled chunk
    f32x4 acc[4][4] = {};

    const int srow = tid >> 2;
    const int cg = (tid & 3) ^ ((srow >> 1) & 3); // global chunk (same for row+64)
    const bf16_t* gA = A + (size_t)(m0 + srow) * K + cg * 8;
    const bf16_t* gB = Bt + (size_t)(n0 + srow) * K + cg * 8;
    bf16_t* lA = &As[tid * 8];
    bf16_t* lB = &Bs[tid * 8];
    constexpr int HGAP = 64 * K;

    for (int kt = 0; kt < K; kt += 32) {
        __syncthreads();
        async_copy16(gA + kt, lA);
        async_copy16(gA + HGAP + kt, lA + 2048);
        async_copy16(gB + kt, lB);
        async_copy16(gB + HGAP + kt, lB + 2048);
        __syncthreads();
        bf16x8 af[4], bfr[4];
#pragma unroll
        for (int mi = 0; mi < 4; mi++)
            af[mi] = *(const bf16x8*)(&As[(wm + mi * 16 + l15) * 32 + fsw * 8]);
#pragma unroll
        for (int ni = 0; ni < 4; ni++)
            bfr[ni] = *(const bf16x8*)(&Bs[(wn + ni * 16 + l15) * 32 + fsw * 8]);
#pragma unroll
        for (int mi = 0; mi < 4; mi++)
#pragma unroll
            for (int ni = 0; ni < 4; ni++)
                acc[mi][ni] = __builtin_amdgcn_mfma_f32_16x16x32_bf16(
                    af[mi], bfr[ni], acc[mi][ni], 0, 0, 0);
    }

    if (NORM && n0 < 2048) {   // wave's 64-col span == one head: fused F.normalize
#pragma unroll
        for (int mi = 0; mi < 4; mi++)
#pragma unroll
            for (int r = 0; r < 4; r++) {
                float s = 0.f;
#pragma unroll
                for (int ni = 0; ni < 4; ni++) {
                    float v = acc[mi][ni][r];
                    s += v * v;
                }
                s += __shfl_xor(s, 1);
                s += __shfl_xor(s, 2);
                s += __shfl_xor(s, 4);
                s += __shfl_xor(s, 8);
                float sc = 1.0f / fmaxf(sqrtf(s), 1e-12f);
#pragma unroll
                for (int ni = 0; ni < 4; ni++) acc[mi][ni][r] *= sc;
            }
    }
#pragma unroll
    for (int mi = 0; mi < 4; mi++)
#pragma unroll
        for (int ni = 0; ni < 4; ni++)
#pragma unroll
            for (int r = 0; r < 4; r++) {
                int row = m0 + wm + mi * 16 + quad * 4 + r;
                int col = n0 + wn + ni * 16 + l15;
                float v = acc[mi][ni][r];
                if (WRITE_F32)
                    ((float*)Cout)[(size_t)row * ldc + col] = v;
                else
                    ((bf16_t*)Cout)[(size_t)row * ldc + col] = (bf16_t)v;
            }
}

// ---------------- V (QKV cols 2048..3071) -> Vt[h][d][n] ----------------
__global__ __launch_bounds__(256) void transpose_v_kernel(const bf16_t* __restrict__ QKV,
                                                          bf16_t* __restrict__ Vt) {
    __shared__ bf16_t t[64][72];
    int n0 = blockIdx.x * 64;
    int h = blockIdx.y;
    int tx = threadIdx.x & 63, ty = threadIdx.x >> 6;
#pragma unroll
    for (int i = 0; i < 16; i++) {
        int nl = ty * 16 + i;
        t[nl][tx] = QKV[(size_t)(n0 + nl) * 3072 + 2048 + h * DH + tx];
    }
    __syncthreads();
#pragma unroll
    for (int i = 0; i < 16; i++) {
        int dl = ty * 16 + i;
        Vt[(size_t)(h * DH + dl) * N_TOK + n0 + tx] = t[tx][dl];
    }
}

// ---------------- flash attention: j-split across 4 waves of one block ----------------
// block = one 32-row i-group of one head; wave w handles j-tiles {w, w+4, ...}.
// Fixed-max softmax => per-wave (acc,l) partials combine by pure addition in LDS.
#define OC_STRIDE 68
__global__ __launch_bounds__(256, 4) void attn_kernel(const bf16_t* __restrict__ QKV,
                                                      const bf16_t* __restrict__ Vt,
                                                      bf16_t* __restrict__ O) {
    __shared__ __align__(16) char lds[4 * 32 * OC_STRIDE * 4 + 4 * 32 * 4];
    const int tid = threadIdx.x;
    const int wave = tid >> 6;
    const int lane = tid & 63;
    const int l15 = lane & 15;
    const int quad = lane >> 4;

    const int xcd = blockIdx.x & 7;
    const int t = blockIdx.x >> 3;          // 0..255
    const int h = xcd * 2 + (t & 1);        // 2 heads per XCD for K/V L2 residency
    const int g = 127 - (t >> 1);           // i-group, heaviest first
    const int i0 = g * 32;

    const bf16_t* Qb = QKV + h * DH;
    const bf16_t* Kb = QKV + 1024 + h * DH;
    const bf16_t* Vb = Vt + (size_t)h * DH * N_TOK;
    bf16_t* P = (bf16_t*)lds + wave * 32 * 40;   // wave-private P tile (aliased w/ Oc)

    bf16x8 aq[2][2];
#pragma unroll
    for (int s_ = 0; s_ < 2; s_++)
#pragma unroll
        for (int kd = 0; kd < 2; kd++)
            aq[s_][kd] = *(const bf16x8*)(Qb + (size_t)(i0 + s_ * 16 + l15) * 3072 +
                                          kd * 32 + quad * 8);

    f32x4 acc[2][4] = {};
    float l_part[2][4] = {};

    int jt = wave;
    bf16x8 bk[2][2], bv[4];
    if (jt <= g) {   // preload this wave's first tile
#pragma unroll
        for (int kd = 0; kd < 2; kd++)
#pragma unroll
            for (int jh = 0; jh < 2; jh++)
                bk[kd][jh] = *(const bf16x8*)(Kb + (size_t)(jt * 32 + jh * 16 + l15) * 3072 +
                                              kd * 32 + quad * 8);
#pragma unroll
        for (int ni = 0; ni < 4; ni++)
            bv[ni] = *(const bf16x8*)(Vb + (size_t)(ni * 16 + l15) * N_TOK + jt * 32 + quad * 8);
    }

    for (; jt <= g; jt += 4) {
        // ---- QK^T ----
        f32x4 sS[2][2] = {};
#pragma unroll
        for (int kd = 0; kd < 2; kd++)
#pragma unroll
            for (int s_ = 0; s_ < 2; s_++) {
                sS[s_][0] = __builtin_amdgcn_mfma_f32_16x16x32_bf16(aq[s_][kd], bk[kd][0], sS[s_][0], 0, 0, 0);
                sS[s_][1] = __builtin_amdgcn_mfma_f32_16x16x32_bf16(aq[s_][kd], bk[kd][1], sS[s_][1], 0, 0, 0);
            }
        if (jt + 4 <= g) {   // prefetch next K fragments
            const bf16_t* kn = Kb + (size_t)(jt + 4) * 32 * 3072;
#pragma unroll
            for (int kd = 0; kd < 2; kd++)
#pragma unroll
                for (int jh = 0; jh < 2; jh++)
                    bk[kd][jh] = *(const bf16x8*)(kn + (size_t)(jh * 16 + l15) * 3072 +
                                                  kd * 32 + quad * 8);
        }
        // ---- softmax (fixed max) + P store ----
        if (jt == g) {                        // diagonal tile: causal mask (i0 == j0)
#pragma unroll
            for (int s_ = 0; s_ < 2; s_++)
#pragma unroll
                for (int r = 0; r < 4; r++) {
                    const int il = s_ * 16 + quad * 4 + r;
                    float p0 = (l15 > il) ? 0.f : __builtin_amdgcn_exp2f(sS[s_][0][r] * C1 - C2);
                    float p1 = (16 + l15 > il) ? 0.f : __builtin_amdgcn_exp2f(sS[s_][1][r] * C1 - C2);
                    l_part[s_][r] += p0 + p1;
                    P[il * 40 + l15] = (bf16_t)p0;
                    P[il * 40 + 16 + l15] = (bf16_t)p1;
                }
        } else {
#pragma unroll
            for (int s_ = 0; s_ < 2; s_++)
#pragma unroll
                for (int r = 0; r < 4; r++) {
                    const int il = s_ * 16 + quad * 4 + r;
                    float p0 = __builtin_amdgcn_exp2f(sS[s_][0][r] * C1 - C2);
                    float p1 = __builtin_amdgcn_exp2f(sS[s_][1][r] * C1 - C2);
                    l_part[s_][r] += p0 + p1;
                    P[il * 40 + l15] = (bf16_t)p0;
                    P[il * 40 + 16 + l15] = (bf16_t)p1;
                }
        }
        // ---- P (C-layout) -> A-layout via wave-private LDS; PV ----
#pragma unroll
        for (int s_ = 0; s_ < 2; s_++) {
            bf16x8 ap = *(const bf16x8*)(&P[(s_ * 16 + l15) * 40 + quad * 8]);
#pragma unroll
            for (int ni = 0; ni < 4; ni++)
                acc[s_][ni] = __builtin_amdgcn_mfma_f32_16x16x32_bf16(ap, bv[ni], acc[s_][ni], 0, 0, 0);
        }
        if (jt + 4 <= g) {   // prefetch next V fragments
            const bf16_t* vn = Vb + (jt + 4) * 32;
#pragma unroll
            for (int ni = 0; ni < 4; ni++)
                bv[ni] = *(const bf16x8*)(vn + (size_t)(ni * 16 + l15) * N_TOK + quad * 8);
        }
    }

    // ---- combine the 4 waves' partials via LDS (pure adds; fixed-max softmax) ----
    __syncthreads();                          // P region dead; reuse as Oc
    float* Oc = (float*)lds;                  // [4][32][OC_STRIDE]
    float* Lc = (float*)(lds + 4 * 32 * OC_STRIDE * 4);   // [4][32]
#pragma unroll
    for (int s_ = 0; s_ < 2; s_++)
#pragma unroll
        for (int ni = 0; ni < 4; ni++)
#pragma unroll
            for (int r = 0; r < 4; r++)
                Oc[(wave * 32 + s_ * 16 + quad * 4 + r) * OC_STRIDE + ni * 16 + l15] = acc[s_][ni][r];
    // l_part is a per-lane partial over columns {l15, 16+l15}: reduce across the
    // 16-lane column group BEFORE storing (round-5 bug: this reduction was missing).
#pragma unroll
    for (int s_ = 0; s_ < 2; s_++)
#pragma unroll
        for (int r = 0; r < 4; r++) {
            float l = l_part[s_][r];
            l += __shfl_xor(l, 1);
            l += __shfl_xor(l, 2);
            l += __shfl_xor(l, 4);
            l += __shfl_xor(l, 8);
            if (l15 == 0)
                Lc[wave * 32 + s_ * 16 + quad * 4 + r] = l;
        }
    __syncthreads();
    const int row = tid >> 3;                 // 0..31
    const int cg0 = (tid & 7) * 8;            // 8 cols per thread
    float l = Lc[row] + Lc[32 + row] + Lc[64 + row] + Lc[96 + row];
    float inv = 1.0f / l;
    f32x4 s0 = *(const f32x4*)(&Oc[row * OC_STRIDE + cg0]);
    f32x4 s1 = *(const f32x4*)(&Oc[row * OC_STRIDE + cg0 + 4]);
#pragma unroll
    for (int w = 1; w < 4; w++) {
        s0 += *(const f32x4*)(&Oc[(w * 32 + row) * OC_STRIDE + cg0]);
        s1 += *(const f32x4*)(&Oc[(w * 32 + row) * OC_STRIDE + cg0 + 4]);
    }
    bf16x8 o;
#pragma unroll
    for (int j = 0; j < 4; j++) { o[j] = (bf16_t)(s0[j] * inv); o[4 + j] = (bf16_t)(s1[j] * inv); }
    *(bf16x8*)(&O[(size_t)(i0 + row) * D_MODEL + h * DH + cg0]) = o;
}

extern "C" void kernel_launch(void* const* d_in, const int* in_sizes, int n_in,
                              void* d_out, int out_size, void* d_ws, size_t ws_size,
                              hipStream_t stream) {
    const float* x  = (const float*)d_in[0];
    const float* Wq = (const float*)d_in[1];
    const float* Wk = (const float*)d_in[2];
    const float* Wv = (const float*)d_in[3];
    const float* Wo = (const float*)d_in[4];
    float* out = (float*)d_out;
    char* ws = (char*)d_ws;
    const size_t MB = 1024 * 1024;
    bf16_t* xb   = (bf16_t*)(ws);             // 8 MB
    bf16_t* Wt3  = (bf16_t*)(ws + 8 * MB);    // 6 MB  [3072][1024] q|k|v
    bf16_t* Wot  = (bf16_t*)(ws + 14 * MB);   // 2 MB
    bf16_t* QKV  = (bf16_t*)(ws + 16 * MB);   // 24 MB [4096][3072]
    bf16_t* Vt   = (bf16_t*)(ws + 40 * MB);   // 8 MB  [16][64][4096]
    bf16_t* Ob   = (bf16_t*)(ws + 48 * MB);   // 8 MB  -> ends at 56 MB

    cast_x_kernel<<<4096, 256, 0, stream>>>(x, xb);
    dim3 gw(16, 16, 4);
    transpose_w_kernel<<<gw, 256, 0, stream>>>(Wq, Wk, Wv, Wo,
                                               Wt3, Wt3 + 1024 * 1024, Wt3 + 2 * 1024 * 1024, Wot);
    dim3 gqkv(3072 / 128, N_TOK / 128);
    gemm_tile<0, 1><<<gqkv, 256, 0, stream>>>(xb, Wt3, QKV, 3072);
    dim3 gv(N_TOK / 64, HEADS);
    transpose_v_kernel<<<gv, 256, 0, stream>>>(QKV, Vt);
    attn_kernel<<<2048, 256, 0, stream>>>(QKV, Vt, Ob);
    dim3 go(D_MODEL / 128, N_TOK / 128);
    gemm_tile<1, 0><<<go, 256, 0, stream>>>(Ob, Wot, out, D_MODEL);
}